// Round 6
// baseline (67.306 us; speedup 1.0000x reference)
//
#include <hip/hip_runtime.h>

#define HH 4096
#define WW 4096
#define MAXK (1 << 20)          // == NRS * 16
#define NSP 16                  // 256-px spans per row
#define SPW 256                 // span width in px
#define RR 8                    // rows per strip-wave
#define NRS (HH * NSP)          // 65536 row-spans
#define NWAVE ((HH / RR) * NSP) // 8192 strip-waves
#define NBLK1 (NWAVE / 4)       // 2048 blocks for k_maxima

typedef int v4i __attribute__((ext_vector_type(4)));

// ---------------------------------------------------------------------------
// Kernel 1: 3x3 NMS. Each WAVE owns an 8-row x 256-col strip; lane owns 4 px.
// Rolling 3-row register window, shfl horizontal halo, no LDS, no barriers.
// Clamp-to-edge == -inf SAME padding for a max filter.
// ---------------------------------------------------------------------------
__global__ __launch_bounds__(256, 4) void k_maxima(
    const float* __restrict__ rel, const float* __restrict__ rep,
    int* __restrict__ mx, unsigned char* __restrict__ masks,
    int* __restrict__ counts)
{
    const int tid  = threadIdx.x;
    const int lane = tid & 63;
    const int wv   = blockIdx.x * 4 + (tid >> 6);
    const int span = wv & (NSP - 1);
    const int y0   = (wv >> 4) * RR;
    const int x0   = span * SPW + lane * 4;

    const int xl = span ? span * SPW - 1 : 0;                     // left halo col
    const int xr = (span < NSP - 1) ? span * SPW + SPW : WW - 1;  // right halo col
    const int hx = (lane == 63) ? xr : xl;   // 2 cache lines, broadcast

    const int ya = y0 ? y0 - 1 : 0;
    const float* pA = rep + (size_t)ya * WW;
    const float* pB = rep + (size_t)y0 * WW;

    float4 A  = *reinterpret_cast<const float4*>(pA + x0);
    float  hA = pA[hx];
    float4 B  = *reinterpret_cast<const float4*>(pB + x0);
    float  hB = pB[hx];

#pragma unroll
    for (int r = 0; r < RR; ++r) {
        const int yc = y0 + r;                       // center row
        const int yn = (yc + 1 < HH) ? yc + 1 : HH - 1;
        const float* pC = rep + (size_t)yn * WW;
        // next-row loads: independent of this row's compute -> pipelined
        float4 C  = *reinterpret_cast<const float4*>(pC + x0);
        float  hC = pC[hx];
        float4 V  = *reinterpret_cast<const float4*>(rel + (size_t)yc * WW + x0);

        // vertical 3-max
        const float vm0 = fmaxf(fmaxf(A.x, B.x), C.x);
        const float vm1 = fmaxf(fmaxf(A.y, B.y), C.y);
        const float vm2 = fmaxf(fmaxf(A.z, B.z), C.z);
        const float vm3 = fmaxf(fmaxf(A.w, B.w), C.w);
        const float hvm = fmaxf(fmaxf(hA, hB), hC);

        // horizontal halo via wave shuffles
        float left  = __shfl_up(vm3, 1, 64);
        float right = __shfl_down(vm0, 1, 64);
        if (lane == 0)  left  = hvm;
        if (lane == 63) right = hvm;

        const float m30 = fmaxf(fmaxf(left, vm0), vm1);
        const float m31 = fmaxf(fmaxf(vm0, vm1), vm2);
        const float m32 = fmaxf(fmaxf(vm1, vm2), vm3);
        const float m33 = fmaxf(fmaxf(vm2, vm3), right);

        unsigned int mask = 0;
        if (B.x == m30 && B.x >= 0.7f && V.x >= 0.7f) mask |= 1u;
        if (B.y == m31 && B.y >= 0.7f && V.y >= 0.7f) mask |= 2u;
        if (B.z == m32 && B.z >= 0.7f && V.z >= 0.7f) mask |= 4u;
        if (B.w == m33 && B.w >= 0.7f && V.w >= 0.7f) mask |= 8u;

        // maxima as int32 0/1, lane-contiguous, nontemporal (never re-read)
        v4i o;
        o.x = mask & 1u; o.y = (mask >> 1) & 1u;
        o.z = (mask >> 2) & 1u; o.w = (mask >> 3) & 1u;
        __builtin_nontemporal_store(o,
            reinterpret_cast<v4i*>(mx + (size_t)yc * WW + x0));

        const int rs = yc * NSP + span;
        if (masks) masks[(size_t)rs * 64 + lane] = (unsigned char)mask;

        // per-row count via ballots (scalar pipe), lane 0 stores
        const unsigned long long b0 = __ballot(mask & 1u);
        const unsigned long long b1 = __ballot(mask & 2u);
        const unsigned long long b2 = __ballot(mask & 4u);
        const unsigned long long b3 = __ballot(mask & 8u);
        if (lane == 0)
            counts[rs] = __popcll(b0) + __popcll(b1) + __popcll(b2) + __popcll(b3);

        A = B; hA = hB; B = C; hB = hC;   // roll the window
    }
}

// ---------------------------------------------------------------------------
// Kernel 2: exclusive scan of 65536 row-span counts. One block, 1024 threads,
// 64 counts/thread. offsets[NRS] = total.
// ---------------------------------------------------------------------------
__global__ __launch_bounds__(1024) void k_scan(const int* __restrict__ counts,
                                               int* __restrict__ offsets)
{
    const int tid  = threadIdx.x;
    const int lane = tid & 63, wid = tid >> 6;   // 16 waves

    int v[64];
    int tot = 0;
    const int4* src = reinterpret_cast<const int4*>(counts + tid * 64);
#pragma unroll
    for (int i = 0; i < 16; ++i) {
        int4 a = src[i];
        v[4 * i] = a.x; v[4 * i + 1] = a.y; v[4 * i + 2] = a.z; v[4 * i + 3] = a.w;
        tot += a.x + a.y + a.z + a.w;
    }

    int inc = tot;
#pragma unroll
    for (int off = 1; off < 64; off <<= 1) {
        int n = __shfl_up(inc, off, 64);
        if (lane >= off) inc += n;
    }
    __shared__ int wsum[16];
    if (lane == 63) wsum[wid] = inc;
    __syncthreads();
    int wbase = 0;
    for (int w = 0; w < wid; ++w) wbase += wsum[w];

    int run = wbase + inc - tot;
    int4* dst = reinterpret_cast<int4*>(offsets + tid * 64);
#pragma unroll
    for (int i = 0; i < 16; ++i) {
        int4 o;
        o.x = run; run += v[4 * i];
        o.y = run; run += v[4 * i + 1];
        o.z = run; run += v[4 * i + 2];
        o.w = run; run += v[4 * i + 3];
        dst[i] = o;
    }
    if (tid == 1023) offsets[NRS] = run;   // total keypoint count
}

// ---------------------------------------------------------------------------
// Kernel 3a: ordered compaction, one WAVE per row-span, no LDS/barriers.
// Fused -1 tail fill: row-span rs owns coord slots [rs*16, rs*16+16).
// ---------------------------------------------------------------------------
__global__ __launch_bounds__(256) void k_emit_ws(
    const unsigned char* __restrict__ masks, const int* __restrict__ offsets,
    int* __restrict__ oy, int* __restrict__ ox)
{
    const int tid  = threadIdx.x;
    const int lane = tid & 63;
    const int rs   = blockIdx.x * 4 + (tid >> 6);

    const int total = offsets[NRS];
    if (lane < 16) {
        const int slot = rs * 16 + lane;
        if (slot >= total) { oy[slot] = -1; ox[slot] = -1; }
    }

    unsigned int mask = masks[(size_t)rs * 64 + lane];

    const int cnt = __popc(mask);
    int inc = cnt;
#pragma unroll
    for (int off = 1; off < 64; off <<= 1) {
        int n = __shfl_up(inc, off, 64);
        if (lane >= off) inc += n;
    }

    int pos = offsets[rs] + inc - cnt;
    const int y  = rs >> 4;
    const int xb = (rs & 15) * SPW + lane * 4;
    while (mask) {
        int b = __ffs(mask) - 1;
        mask &= mask - 1;
        if (pos < MAXK) { oy[pos] = y; ox[pos] = xb + b; }
        ++pos;
    }
}

// ---------------------------------------------------------------------------
// Kernel 3b: fallback — rebuild masks from the int32 maxima array.
// ---------------------------------------------------------------------------
__global__ __launch_bounds__(256) void k_emit_mx(
    const int* __restrict__ mx, const int* __restrict__ offsets,
    int* __restrict__ oy, int* __restrict__ ox)
{
    const int tid  = threadIdx.x;
    const int lane = tid & 63;
    const int rs   = blockIdx.x * 4 + (tid >> 6);

    const int total = offsets[NRS];
    if (lane < 16) {
        const int slot = rs * 16 + lane;
        if (slot >= total) { oy[slot] = -1; ox[slot] = -1; }
    }

    const int y  = rs >> 4;
    const int xb = (rs & 15) * SPW + lane * 4;
    const int4 f = *reinterpret_cast<const int4*>(mx + (size_t)y * WW + xb);
    unsigned int mask = 0;
    if (f.x) mask |= 1u;
    if (f.y) mask |= 2u;
    if (f.z) mask |= 4u;
    if (f.w) mask |= 8u;

    const int cnt = __popc(mask);
    int inc = cnt;
#pragma unroll
    for (int off = 1; off < 64; off <<= 1) {
        int n = __shfl_up(inc, off, 64);
        if (lane >= off) inc += n;
    }

    int pos = offsets[rs] + inc - cnt;
    while (mask) {
        int b = __ffs(mask) - 1;
        mask &= mask - 1;
        if (pos < MAXK) { oy[pos] = y; ox[pos] = xb + b; }
        ++pos;
    }
}

// ---------------------------------------------------------------------------
extern "C" void kernel_launch(void* const* d_in, const int* in_sizes, int n_in,
                              void* d_out, int out_size, void* d_ws, size_t ws_size,
                              hipStream_t stream)
{
    const float* rel = (const float*)d_in[0];   // reliability
    const float* rep = (const float*)d_in[1];   // repeatability

    int* out = (int*)d_out;
    int* mx  = out;                       // 4096*4096 maxima (int32 0/1)
    int* oy  = out + (size_t)HH * WW;     // 2^20 y coords
    int* ox  = oy + MAXK;                 // 2^20 x coords

    int* counts  = (int*)d_ws;                        // NRS ints
    int* offsets = counts + NRS;                      // NRS+1 ints (+pad)
    unsigned char* masks = (unsigned char*)(offsets + NRS + 4);  // NRS*64 B

    const size_t need_ws = (size_t)(2 * NRS + 4) * sizeof(int)
                         + (size_t)NRS * 64;
    const bool use_masks = ws_size >= need_ws;

    k_maxima<<<NBLK1, 256, 0, stream>>>(rel, rep, mx,
                                        use_masks ? masks : nullptr, counts);
    k_scan<<<1, 1024, 0, stream>>>(counts, offsets);
    if (use_masks)
        k_emit_ws<<<NRS / 4, 256, 0, stream>>>(masks, offsets, oy, ox);
    else
        k_emit_mx<<<NRS / 4, 256, 0, stream>>>(mx, offsets, oy, ox);
}

// Round 7
// 67.209 us; speedup vs baseline: 1.0015x; 1.0015x over previous
//
#include <hip/hip_runtime.h>

#define HH 4096
#define WW 4096
#define MAXK (1 << 20)          // == NRS * 16
#define NSP 16                  // 256-px spans per row
#define SPW 256                 // span width in px
#define RR 8                    // rows per strip-wave
#define NRS (HH * NSP)          // 65536 row-spans
#define NWAVE ((HH / RR) * NSP) // 8192 strip-waves
#define NBLK1 (NWAVE / 4)       // 2048 blocks for k_maxima

typedef int   v4i __attribute__((ext_vector_type(4)));
typedef float v4f __attribute__((ext_vector_type(4)));

// Volatile asm loads: compiler cannot sink, reorder, or register-minimize.
// Data is NOT ready until our explicit s_waitcnt vmcnt(0).
__device__ __forceinline__ v4f gload4(const float* p) {
    v4f d;
    asm volatile("global_load_dwordx4 %0, %1, off" : "=v"(d) : "v"(p));
    return d;
}
__device__ __forceinline__ float gload1(const float* p) {
    float d;
    asm volatile("global_load_dword %0, %1, off" : "=v"(d) : "v"(p));
    return d;
}

// ---------------------------------------------------------------------------
// Kernel 1: 3x3 NMS. Each WAVE owns an 8-row x 256-col strip; lane owns 4 px.
// Phase 1: issue ALL 28 strip loads via inline asm (forced MLP).
// Phase 2: single vmcnt(0) + sched_barrier, then branch-free compute.
// Clamp-to-edge == -inf SAME padding for a max filter.
// ---------------------------------------------------------------------------
__global__ __launch_bounds__(256) void k_maxima(
    const float* __restrict__ rel, const float* __restrict__ rep,
    int* __restrict__ mx, unsigned int* __restrict__ masksP,
    int* __restrict__ counts)
{
    const int tid  = threadIdx.x;
    const int lane = tid & 63;
    const int wv   = blockIdx.x * 4 + (tid >> 6);
    const int span = wv & (NSP - 1);
    const int y0   = (wv >> 4) * RR;
    const int x0   = span * SPW + lane * 4;

    const int xl = span ? span * SPW - 1 : 0;                    // left halo col
    const int xr = (span < NSP - 1) ? (span + 1) * SPW : WW - 1; // right halo col
    const int hx = (lane == 63) ? xr : xl;   // 2 cache lines, broadcast

    // ---- phase 1: issue ALL loads (28 VMEM ops in flight) ----
    v4f R[RR + 2]; float hR[RR + 2]; v4f L[RR];
#pragma unroll
    for (int i = 0; i < RR + 2; ++i) {
        int yy = y0 - 1 + i;
        yy = yy < 0 ? 0 : (yy >= HH ? HH - 1 : yy);
        const float* row = rep + (size_t)yy * WW;
        R[i]  = gload4(row + x0);
        hR[i] = gload1(row + hx);
    }
#pragma unroll
    for (int i = 0; i < RR; ++i)
        L[i] = gload4(rel + (size_t)(y0 + i) * WW + x0);

    asm volatile("s_waitcnt vmcnt(0)" ::: "memory");
    __builtin_amdgcn_sched_barrier(0);

    // ---- phase 2: compute all 8 rows from registers ----
    unsigned int packed = 0;
    int myc = 0;
#pragma unroll
    for (int r = 0; r < RR; ++r) {
        const v4f A = R[r], B = R[r + 1], C = R[r + 2];
        const v4f V = L[r];

        const float vm0 = fmaxf(fmaxf(A.x, B.x), C.x);
        const float vm1 = fmaxf(fmaxf(A.y, B.y), C.y);
        const float vm2 = fmaxf(fmaxf(A.z, B.z), C.z);
        const float vm3 = fmaxf(fmaxf(A.w, B.w), C.w);
        const float hvm = fmaxf(fmaxf(hR[r], hR[r + 1]), hR[r + 2]);

        float left  = __shfl_up(vm3, 1, 64);
        float right = __shfl_down(vm0, 1, 64);
        if (lane == 0)  left  = hvm;
        if (lane == 63) right = hvm;

        const float m30 = fmaxf(fmaxf(left, vm0), vm1);
        const float m31 = fmaxf(fmaxf(vm0, vm1), vm2);
        const float m32 = fmaxf(fmaxf(vm1, vm2), vm3);
        const float m33 = fmaxf(fmaxf(vm2, vm3), right);

        unsigned int mask = 0;
        if (B.x == m30 && B.x >= 0.7f && V.x >= 0.7f) mask |= 1u;
        if (B.y == m31 && B.y >= 0.7f && V.y >= 0.7f) mask |= 2u;
        if (B.z == m32 && B.z >= 0.7f && V.z >= 0.7f) mask |= 4u;
        if (B.w == m33 && B.w >= 0.7f && V.w >= 0.7f) mask |= 8u;

        v4i o;
        o.x = mask & 1u;        o.y = (mask >> 1) & 1u;
        o.z = (mask >> 2) & 1u; o.w = (mask >> 3) & 1u;
        __builtin_nontemporal_store(o,
            reinterpret_cast<v4i*>(mx + (size_t)(y0 + r) * WW + x0));

        packed |= mask << (4 * r);

        const int cnt = __popcll(__ballot(mask & 1u)) + __popcll(__ballot(mask & 2u))
                      + __popcll(__ballot(mask & 4u)) + __popcll(__ballot(mask & 8u));
        if (lane == r) myc = cnt;   // lane r carries row r's count
    }

    // one dword store per lane: 8 row-masks packed (4 bits each)
    if (masksP) masksP[(size_t)wv * 64 + lane] = packed;
    // one exec-masked store: lanes 0..7 write their row's count
    if (lane < RR) counts[(y0 + lane) * NSP + span] = myc;
}

// ---------------------------------------------------------------------------
// Kernel 2: exclusive scan of 65536 row-span counts. One block, 1024 threads,
// 64 counts/thread. offsets[NRS] = total.
// ---------------------------------------------------------------------------
__global__ __launch_bounds__(1024) void k_scan(const int* __restrict__ counts,
                                               int* __restrict__ offsets)
{
    const int tid  = threadIdx.x;
    const int lane = tid & 63, wid = tid >> 6;   // 16 waves

    int v[64];
    int tot = 0;
    const int4* src = reinterpret_cast<const int4*>(counts + tid * 64);
#pragma unroll
    for (int i = 0; i < 16; ++i) {
        int4 a = src[i];
        v[4 * i] = a.x; v[4 * i + 1] = a.y; v[4 * i + 2] = a.z; v[4 * i + 3] = a.w;
        tot += a.x + a.y + a.z + a.w;
    }

    int inc = tot;
#pragma unroll
    for (int off = 1; off < 64; off <<= 1) {
        int n = __shfl_up(inc, off, 64);
        if (lane >= off) inc += n;
    }
    __shared__ int wsum[16];
    if (lane == 63) wsum[wid] = inc;
    __syncthreads();
    int wbase = 0;
    for (int w = 0; w < wid; ++w) wbase += wsum[w];

    int run = wbase + inc - tot;
    int4* dst = reinterpret_cast<int4*>(offsets + tid * 64);
#pragma unroll
    for (int i = 0; i < 16; ++i) {
        int4 o;
        o.x = run; run += v[4 * i];
        o.y = run; run += v[4 * i + 1];
        o.z = run; run += v[4 * i + 2];
        o.w = run; run += v[4 * i + 3];
        dst[i] = o;
    }
    if (tid == 1023) offsets[NRS] = run;   // total keypoint count
}

// ---------------------------------------------------------------------------
// Kernel 3a: ordered compaction from packed masks, one WAVE per row-span.
// Fused -1 tail fill: row-span rs owns coord slots [rs*16, rs*16+16).
// ---------------------------------------------------------------------------
__global__ __launch_bounds__(256) void k_emit_ws(
    const unsigned int* __restrict__ masksP, const int* __restrict__ offsets,
    int* __restrict__ oy, int* __restrict__ ox)
{
    const int tid  = threadIdx.x;
    const int lane = tid & 63;
    const int rs   = blockIdx.x * 4 + (tid >> 6);
    const int y    = rs >> 4;
    const int span = rs & (NSP - 1);
    const int sid  = (y >> 3) * NSP + span;   // strip-wave id
    const int r    = y & 7;

    const int total = offsets[NRS];
    if (lane < 16) {
        const int slot = rs * 16 + lane;
        if (slot >= total) { oy[slot] = -1; ox[slot] = -1; }
    }

    unsigned int mask = (masksP[(size_t)sid * 64 + lane] >> (4 * r)) & 0xFu;

    const int cnt = __popc(mask);
    int inc = cnt;
#pragma unroll
    for (int off = 1; off < 64; off <<= 1) {
        int n = __shfl_up(inc, off, 64);
        if (lane >= off) inc += n;
    }

    int pos = offsets[rs] + inc - cnt;
    const int xb = span * SPW + lane * 4;
    while (mask) {
        int b = __ffs(mask) - 1;
        mask &= mask - 1;
        if (pos < MAXK) { oy[pos] = y; ox[pos] = xb + b; }
        ++pos;
    }
}

// ---------------------------------------------------------------------------
// Kernel 3b: fallback — rebuild masks from the int32 maxima array.
// ---------------------------------------------------------------------------
__global__ __launch_bounds__(256) void k_emit_mx(
    const int* __restrict__ mx, const int* __restrict__ offsets,
    int* __restrict__ oy, int* __restrict__ ox)
{
    const int tid  = threadIdx.x;
    const int lane = tid & 63;
    const int rs   = blockIdx.x * 4 + (tid >> 6);

    const int total = offsets[NRS];
    if (lane < 16) {
        const int slot = rs * 16 + lane;
        if (slot >= total) { oy[slot] = -1; ox[slot] = -1; }
    }

    const int y  = rs >> 4;
    const int xb = (rs & (NSP - 1)) * SPW + lane * 4;
    const int4 f = *reinterpret_cast<const int4*>(mx + (size_t)y * WW + xb);
    unsigned int mask = 0;
    if (f.x) mask |= 1u;
    if (f.y) mask |= 2u;
    if (f.z) mask |= 4u;
    if (f.w) mask |= 8u;

    const int cnt = __popc(mask);
    int inc = cnt;
#pragma unroll
    for (int off = 1; off < 64; off <<= 1) {
        int n = __shfl_up(inc, off, 64);
        if (lane >= off) inc += n;
    }

    int pos = offsets[rs] + inc - cnt;
    while (mask) {
        int b = __ffs(mask) - 1;
        mask &= mask - 1;
        if (pos < MAXK) { oy[pos] = y; ox[pos] = xb + b; }
        ++pos;
    }
}

// ---------------------------------------------------------------------------
extern "C" void kernel_launch(void* const* d_in, const int* in_sizes, int n_in,
                              void* d_out, int out_size, void* d_ws, size_t ws_size,
                              hipStream_t stream)
{
    const float* rel = (const float*)d_in[0];   // reliability
    const float* rep = (const float*)d_in[1];   // repeatability

    int* out = (int*)d_out;
    int* mx  = out;                       // 4096*4096 maxima (int32 0/1)
    int* oy  = out + (size_t)HH * WW;     // 2^20 y coords
    int* ox  = oy + MAXK;                 // 2^20 x coords

    int* counts  = (int*)d_ws;                        // NRS ints
    int* offsets = counts + NRS;                      // NRS+1 ints (+pad)
    unsigned int* masksP = (unsigned int*)(offsets + NRS + 4);  // NWAVE*64 u32

    const size_t need_ws = (size_t)(2 * NRS + 4) * sizeof(int)
                         + (size_t)NWAVE * 64 * sizeof(unsigned int);
    const bool use_masks = ws_size >= need_ws;

    k_maxima<<<NBLK1, 256, 0, stream>>>(rel, rep, mx,
                                        use_masks ? masksP : nullptr, counts);
    k_scan<<<1, 1024, 0, stream>>>(counts, offsets);
    if (use_masks)
        k_emit_ws<<<NRS / 4, 256, 0, stream>>>(masksP, offsets, oy, ox);
    else
        k_emit_mx<<<NRS / 4, 256, 0, stream>>>(mx, offsets, oy, ox);
}